// Round 5
// baseline (687.503 us; speedup 1.0000x reference)
//
#include <hip/hip_runtime.h>
#include <cstdint>
#include <cstddef>
#include <math.h>

// Problem constants (match reference: B,C,N,K = 16,64,2048,20)
#define BB 16
#define CC 64
#define NN 2048
#define KK 20
#define K2 14   // ceil(20*2/3)
#define TQ 8    // queries per block in knn kernel (one per wave)
#define NC 26   // fp32 candidate count (margin over K=20 for approx->fp64 rank safety)
#define SP 2052 // pd row stride: 4*SP%32==16 -> conflict-free MFMA C-scatter

// native clang vector types
typedef float nfloat4 __attribute__((ext_vector_type(4)));
typedef __attribute__((ext_vector_type(8))) short bf16x8;
typedef __attribute__((ext_vector_type(4))) float f32x4;
typedef unsigned short u16;

// RNE float -> bf16
static __device__ __forceinline__ u16 f2bf(float f) {
    unsigned u = __float_as_uint(f);
    return (u16)((u + 0x7fffu + ((u >> 16) & 1u)) >> 16);
}

// ---------------------------------------------------------------------------
// prep: xt[b][n][c] = x[b][c][n] (fp32), bf16 hi/lo split arrays xth/xtl
// (point-major, MFMA-ready), plus norms in fp64+fp32.
// ---------------------------------------------------------------------------
__global__ __launch_bounds__(256) void prep_kernel(const float* __restrict__ x,
                                                   float* __restrict__ xt,
                                                   u16* __restrict__ xth,
                                                   u16* __restrict__ xtl,
                                                   float* __restrict__ xxf,
                                                   double* __restrict__ xxd) {
    __shared__ float s_t[64][65];
    int b = blockIdx.x >> 5;
    int n0 = (blockIdx.x & 31) * 64;
    const float* xb = x + (size_t)b * CC * NN;
    int tid = threadIdx.x;
    int cq = tid >> 6;
    int nl = tid & 63;

#pragma unroll
    for (int r = 0; r < 16; ++r) {
        int c = r * 4 + cq;
        s_t[c][nl] = xb[c * NN + n0 + nl];
    }
    __syncthreads();

#pragma unroll
    for (int r = 0; r < 16; ++r) {
        int n = r * 4 + cq;
        float f = s_t[nl][n];
        size_t o = ((size_t)b * NN + n0 + n) * CC + nl;
        xt[o] = f;
        u16 h = f2bf(f);
        float hf = __uint_as_float((unsigned)h << 16);
        u16 l = f2bf(f - hf);
        xth[o] = h;
        xtl[o] = l;
    }

    if (tid < 64) {
        double s = 0.0;
#pragma unroll
        for (int c = 0; c < CC; ++c) {
            double v = (double)s_t[c][tid];
            s += v * v;
        }
        xxd[b * NN + n0 + tid] = s;
        xxf[b * NN + n0 + tid] = (float)s;
    }
}

// ---------------------------------------------------------------------------
// knn v6: 512 threads = 8 waves; 8 queries/block (one per wave); 2 blocks/CU
// (LDS 80.0 KB) so one block's MFMA fill overlaps the other's selection
// latency chains -- v5's 1-block/CU serialization was the regression cause.
// Phase 1: MFMA fill. pd ~= 2*(hh+hl+lh bf16 GEMM) - ||q|| - ||p||.
//   Wave w owns points [w*256, w*256+256): 8 tile-pairs. A-tile rows 8..15
//   duplicate queries 0..7 (ar&7); lanes ag>=2 skip the C-scatter.
//   C layout (verified r2/r4 harness pass): row=(lane>>4)*4+reg -> query,
//   col=lane&15 -> point. Row stride SP=2052: scatter lanes (ag<2, ar, rows
//   r..r+4) spread 32 lanes over 32 banks -> conflict-free.
// Phase 2: per-wave register-resident threshold selection (identical to the
//   602us version): tau = 26th-largest lane-max; survivor compaction +
//   bitonic; exact iterative fallback on mass ties.
// Phase 3: fp64 refine of 26 candidates -> exact top-20 (val desc, idx asc);
//   absorbs the bf16-split approximation error.
// ---------------------------------------------------------------------------
__global__ __launch_bounds__(512, 4) void knn_kernel(const float* __restrict__ x,
                                                     const float* __restrict__ xt,
                                                     const u16* __restrict__ xth,
                                                     const u16* __restrict__ xtl,
                                                     const float* __restrict__ xxf,
                                                     const double* __restrict__ xxd,
                                                     int* __restrict__ idx_ws,
                                                     float* __restrict__ idx_out) {
    __shared__ float s_pd[TQ][SP];                 // 64.1 KiB (padded rows)
    __shared__ __align__(16) float s_xx[NN];       // 8 KiB batch norms
    __shared__ __align__(16) float s_q[CC][TQ];    // 2 KiB query fp32 (phase 3)
    __shared__ float s_sv[TQ][64];                 // survivor values
    __shared__ int   s_si[TQ][64];                 // survivor indices

    int tid = threadIdx.x;
    int b = blockIdx.x >> 8;                       // NN/TQ = 256 blocks/batch
    int n0 = (blockIdx.x & 255) * TQ;
    const float* xb = x + (size_t)b * CC * NN;

    { int c = tid >> 3, qq = tid & 7; s_q[c][qq] = xb[c * NN + n0 + qq]; }
    *(float4*)(&s_xx[tid * 4]) = *(const float4*)(xxf + b * NN + tid * 4);
    __syncthreads();

    int w = tid >> 6;                              // wave id == query id
    int lane = tid & 63;
    int ar = lane & 15, ag = lane >> 4;

    // ---- phase 1: MFMA fill ----
    {
        const u16* xhb = xth + (size_t)b * NN * CC;
        const u16* xlb = xtl + (size_t)b * NN * CC;
        int qrow = n0 + (ar & 7);                  // rows 8..15 duplicate 0..7
        const u16* aph = xhb + (size_t)qrow * CC + ag * 8;
        const u16* apl = xlb + (size_t)qrow * CC + ag * 8;
        bf16x8 ah0 = *(const bf16x8*)(aph);
        bf16x8 ah1 = *(const bf16x8*)(aph + 32);
        bf16x8 al0 = *(const bf16x8*)(apl);
        bf16x8 al1 = *(const bf16x8*)(apl + 32);

        int p0 = w * 256;
        float qn[4];
        int agq = ag & 1;                          // valid for scatter lanes ag<2
#pragma unroll
        for (int r = 0; r < 4; ++r) qn[r] = s_xx[n0 + agq * 4 + r];

#pragma unroll
        for (int tp = 0; tp < 8; ++tp) {
            int pA = p0 + tp * 32 + ar;
            int pB = pA + 16;
            const u16* bphA = xhb + (size_t)pA * CC + ag * 8;
            const u16* bplA = xlb + (size_t)pA * CC + ag * 8;
            const u16* bphB = xhb + (size_t)pB * CC + ag * 8;
            const u16* bplB = xlb + (size_t)pB * CC + ag * 8;
            bf16x8 bh0A = *(const bf16x8*)(bphA);
            bf16x8 bh1A = *(const bf16x8*)(bphA + 32);
            bf16x8 bl0A = *(const bf16x8*)(bplA);
            bf16x8 bl1A = *(const bf16x8*)(bplA + 32);
            bf16x8 bh0B = *(const bf16x8*)(bphB);
            bf16x8 bh1B = *(const bf16x8*)(bphB + 32);
            bf16x8 bl0B = *(const bf16x8*)(bplB);
            bf16x8 bl1B = *(const bf16x8*)(bplB + 32);

            f32x4 accA = {0.f, 0.f, 0.f, 0.f};
            f32x4 accB = {0.f, 0.f, 0.f, 0.f};
            accA = __builtin_amdgcn_mfma_f32_16x16x32_bf16(ah0, bh0A, accA, 0, 0, 0);
            accB = __builtin_amdgcn_mfma_f32_16x16x32_bf16(ah0, bh0B, accB, 0, 0, 0);
            accA = __builtin_amdgcn_mfma_f32_16x16x32_bf16(al0, bh0A, accA, 0, 0, 0);
            accB = __builtin_amdgcn_mfma_f32_16x16x32_bf16(al0, bh0B, accB, 0, 0, 0);
            accA = __builtin_amdgcn_mfma_f32_16x16x32_bf16(ah0, bl0A, accA, 0, 0, 0);
            accB = __builtin_amdgcn_mfma_f32_16x16x32_bf16(ah0, bl0B, accB, 0, 0, 0);
            accA = __builtin_amdgcn_mfma_f32_16x16x32_bf16(ah1, bh1A, accA, 0, 0, 0);
            accB = __builtin_amdgcn_mfma_f32_16x16x32_bf16(ah1, bh1B, accB, 0, 0, 0);
            accA = __builtin_amdgcn_mfma_f32_16x16x32_bf16(al1, bh1A, accA, 0, 0, 0);
            accB = __builtin_amdgcn_mfma_f32_16x16x32_bf16(al1, bh1B, accB, 0, 0, 0);
            accA = __builtin_amdgcn_mfma_f32_16x16x32_bf16(ah1, bl1A, accA, 0, 0, 0);
            accB = __builtin_amdgcn_mfma_f32_16x16x32_bf16(ah1, bl1B, accB, 0, 0, 0);

            float xxA = s_xx[pA];
            float xxB = s_xx[pB];
            if (ag < 2) {
#pragma unroll
                for (int r = 0; r < 4; ++r) {
                    s_pd[ag * 4 + r][pA] = (2.f * accA[r] - qn[r]) - xxA;
                    s_pd[ag * 4 + r][pB] = (2.f * accB[r] - qn[r]) - xxB;
                }
            }
        }
    }
    __syncthreads();

    // ---- phase 2: per-wave selection ----
    int q = w;
    const float* pd = &s_pd[q][0];

    float v[32];
#pragma unroll
    for (int r = 0; r < 32; ++r) v[r] = pd[lane + (r << 6)];   // idx = lane+64r

    float lmax = v[0]; int lr = 0;
#pragma unroll
    for (int r = 1; r < 32; ++r)
        if (v[r] > lmax) { lmax = v[r]; lr = r; }              // strict > : lowest idx

    // tau = 26th-largest lane-max (values-only 64-lane bitonic, descending)
    float sv = lmax;
#pragma unroll
    for (int k = 2; k <= 64; k <<= 1) {
#pragma unroll
        for (int j = k >> 1; j > 0; j >>= 1) {
            float o = __shfl_xor(sv, j);
            bool dird = ((lane & k) == 0);
            bool first = ((lane & j) == 0);
            sv = (first == dird) ? fmaxf(sv, o) : fminf(sv, o);
        }
    }
    float tau = __shfl(sv, 25);

    int cnt = 0;
#pragma unroll
    for (int r = 0; r < 32; ++r) cnt += (v[r] >= tau) ? 1 : 0;
    int incl = cnt;
#pragma unroll
    for (int off = 1; off < 64; off <<= 1) {
        int o = __shfl_up(incl, off);
        if (lane >= off) incl += o;
    }
    int S = __shfl(incl, 63);

    float fv = -INFINITY;
    int fi = 0x7fffffff;
    if (S <= 64) {
        int wr = incl - cnt;
#pragma unroll
        for (int r = 0; r < 32; ++r) {
            if (v[r] >= tau) { s_sv[q][wr] = v[r]; s_si[q][wr] = lane + (r << 6); ++wr; }
        }
        if (lane < S) { fv = s_sv[q][lane]; fi = s_si[q][lane]; }
    } else {
        // pathological (mass ties): exact iterative top-26 extraction
        for (int t = 0; t < NC; ++t) {
            float bv = lmax; int bi = lane + (lr << 6);
#pragma unroll
            for (int off = 32; off; off >>= 1) {
                float ov = __shfl_xor(bv, off);
                int oi = __shfl_xor(bi, off);
                if (ov > bv || (ov == bv && oi < bi)) { bv = ov; bi = oi; }
            }
            if (lane == t) { fv = bv; fi = bi; }
            if ((bi & 63) == lane) {
                int rsel = bi >> 6;
#pragma unroll
                for (int r = 0; r < 32; ++r) if (r == rsel) v[r] = -INFINITY;
                lmax = v[0]; lr = 0;
#pragma unroll
                for (int r = 1; r < 32; ++r)
                    if (v[r] > lmax) { lmax = v[r]; lr = r; }
            }
        }
    }

    // 64-lane bitonic sort of (fv desc, fi asc) -> lanes 0..25 = approx top-26
#pragma unroll
    for (int k = 2; k <= 64; k <<= 1) {
#pragma unroll
        for (int j = k >> 1; j > 0; j >>= 1) {
            float ov = __shfl_xor(fv, j);
            int oi = __shfl_xor(fi, j);
            bool dird = ((lane & k) == 0);
            bool first = ((lane & j) == 0);
            bool better = (fv > ov) || (fv == ov && fi < oi);
            if (better != (first == dird)) { fv = ov; fi = oi; }
        }
    }

    // ---- phase 3: fp64 refine ----
    float* s_c = (float*)&s_pd[q][0];              // reuse dead pd row, 64x27 < SP
    const float* xtb = xt + (size_t)b * NN * CC;
    int nq = n0 + q;

#pragma unroll
    for (int t = 0; t < NC; ++t) {
        int cand = __shfl(fi, t);
        s_c[lane * 27 + t] = xtb[(size_t)cand * CC + lane];   // coalesced row
    }

    double accd = 0.0;
    for (int c = 0; c < CC; ++c) {
        double qc = (double)s_q[c][q];                        // broadcast read
        double cd = (double)s_c[c * 27 + lane];               // conflict-free
        accd = fma(qc, cd, accd);
    }

    double val = -INFINITY;
    int idxq = 0x7fffffff;
    if (lane < NC) {
        val = 2.0 * accd - xxd[b * NN + nq] - xxd[b * NN + fi];
        idxq = fi;
    }

    // 32-lane fp64 bitonic (val desc, idx asc)
#pragma unroll
    for (int k = 2; k <= 32; k <<= 1) {
#pragma unroll
        for (int j = k >> 1; j > 0; j >>= 1) {
            double ov = __shfl_xor(val, j, 32);
            int oi = __shfl_xor(idxq, j, 32);
            bool dird = ((lane & k) == 0);
            bool first = ((lane & j) == 0);
            bool better = (val > ov) || (val == ov && idxq < oi);
            if (better != (first == dird)) { val = ov; idxq = oi; }
        }
    }

    if (lane < KK) {
        size_t obase = ((size_t)b * NN + nq) * KK;
        idx_ws[obase + lane] = idxq;
        idx_out[obase + lane] = (float)(idxq + b * NN);
    }
}

// ---------------------------------------------------------------------------
// x1: mean of top-14 of 20 gathered neighbor values, written channel-major
// as x1t[b][c][n]. (sum20 - six minima)/14, order-independent.
// ---------------------------------------------------------------------------
__global__ __launch_bounds__(256) void x1_kernel(const float* __restrict__ xt,
                                                 const int* __restrict__ idx_ws,
                                                 float* __restrict__ x1t) {
    __shared__ int s_idx[16][KK];
    __shared__ float s_out[64][17];
    int tid = threadIdx.x;
    int b = blockIdx.x >> 7;
    int n0 = (blockIdx.x & 127) * 16;
    const float* xtb = xt + (size_t)b * NN * CC;

    for (int i = tid; i < 16 * KK; i += 256)
        s_idx[i / KK][i % KK] = idx_ws[((size_t)b * NN + n0) * KK + i];
    __syncthreads();

    int pl = tid >> 6, c = tid & 63;
#pragma unroll
    for (int it = 0; it < 4; ++it) {
        int nl = it * 4 + pl;
        float vals[KK];
        float sum = 0.f;
#pragma unroll
        for (int j = 0; j < KK; ++j) {
            vals[j] = xtb[(size_t)s_idx[nl][j] * CC + c];
            sum += vals[j];
        }
#pragma unroll
        for (int t = 0; t < KK - K2; ++t) {
            float worst = INFINITY;
            int wj = 0;
#pragma unroll
            for (int j = 0; j < KK; ++j)
                if (vals[j] < worst) { worst = vals[j]; wj = j; }
            sum -= worst;
            vals[wj] = INFINITY;
        }
        s_out[c][nl] = sum / (float)K2;
    }
    __syncthreads();

    int cw = tid >> 2, nw = (tid & 3) * 4;
    float4 v = make_float4(s_out[cw][nw], s_out[cw][nw + 1],
                           s_out[cw][nw + 2], s_out[cw][nw + 3]);
    *(float4*)(&x1t[((size_t)b * CC + cw) * NN + n0 + nw]) = v;
}

// ---------------------------------------------------------------------------
// feat: float4-vectorized. feature[b,ch,n,j]:
//   ch <  64: x1t[b,ch,idx[b,n,j]] - x[b,ch,n]
//   ch >= 64: x[b,ch-64,n]
// Write-only 335 MB output -> non-temporal stores.
// ---------------------------------------------------------------------------
__global__ __launch_bounds__(256) void feat_kernel(const float* __restrict__ x,
                                                   const float* __restrict__ x1t,
                                                   const int* __restrict__ idx_ws,
                                                   float* __restrict__ out) {
    int bc = blockIdx.x;
    int b = bc >> 7, ch = bc & 127;
    const float* xb = x + (size_t)b * CC * NN;
    float* o = out + (size_t)bc * NN * KK;
    const int* idxb = idx_ws + (size_t)b * NN * KK;

    if (ch < CC) {
        const float* row = x1t + ((size_t)b * CC + ch) * NN;
        const float* xr = xb + ch * NN;
        for (int it = 0; it < 40; ++it) {
            unsigned e = (it * 256 + threadIdx.x) * 4;
            int4 id4 = *(const int4*)(idxb + e);
            nfloat4 o4;
            o4.x = row[id4.x] - xr[(e    ) / KK];
            o4.y = row[id4.y] - xr[(e + 1) / KK];
            o4.z = row[id4.z] - xr[(e + 2) / KK];
            o4.w = row[id4.w] - xr[(e + 3) / KK];
            __builtin_nontemporal_store(o4, (nfloat4*)(o + e));
        }
    } else {
        const float* xr = xb + (ch - CC) * NN;
        for (int it = 0; it < 40; ++it) {
            unsigned e = (it * 256 + threadIdx.x) * 4;
            nfloat4 o4;
            o4.x = xr[(e    ) / KK];
            o4.y = xr[(e + 1) / KK];
            o4.z = xr[(e + 2) / KK];
            o4.w = xr[(e + 3) / KK];
            __builtin_nontemporal_store(o4, (nfloat4*)(o + e));
        }
    }
}

// ---------------------------------------------------------------------------
extern "C" void kernel_launch(void* const* d_in, const int* in_sizes, int n_in,
                              void* d_out, int out_size, void* d_ws, size_t ws_size,
                              hipStream_t stream) {
    const float* x = (const float*)d_in[0];   // (B, C, N) fp32
    float* out = (float*)d_out;

    char* ws = (char*)d_ws;
    float* xt   = (float*)ws;                                   // B*N*C fp32
    float* x1t  = (float*)(ws + (size_t)8388608);               // B*C*N
    double* xxd = (double*)(ws + (size_t)16777216);             // B*N
    float* xxf  = (float*)(ws + (size_t)17039360);              // B*N
    int* idx_ws = (int*)(ws + (size_t)17170432);                // B*N*K

    // bf16 hi/lo split arrays stashed in the out feature region (written by
    // prep, read by knn, overwritten by feat afterwards) -> no ws growth.
    u16* xth = (u16*)out;                                       // B*N*C bf16 (4 MB)
    u16* xtl = (u16*)((char*)out + (size_t)8388608);            // B*N*C bf16 (4 MB)

    float* idx_out = out + (size_t)BB * 2 * CC * NN * KK;       // idx_flat tail

    prep_kernel<<<BB * (NN / 64), 256, 0, stream>>>(x, xt, xth, xtl, xxf, xxd);
    knn_kernel<<<BB * (NN / TQ), 512, 0, stream>>>(x, xt, xth, xtl, xxf, xxd, idx_ws, idx_out);
    x1_kernel<<<BB * (NN / 16), 256, 0, stream>>>(xt, idx_ws, x1t);
    feat_kernel<<<BB * 2 * CC, 256, 0, stream>>>(x, x1t, idx_ws, out);
}

// Round 6
// 593.721 us; speedup vs baseline: 1.1580x; 1.1580x over previous
//
#include <hip/hip_runtime.h>
#include <hip/hip_fp16.h>
#include <cstdint>
#include <cstddef>
#include <math.h>

// Problem constants (match reference: B,C,N,K = 16,64,2048,20)
#define BB 16
#define CC 64
#define NN 2048
#define KK 20
#define K2 14   // ceil(20*2/3)
#define TQ 8    // queries per block in knn kernel (one per wave)
#define NC 26   // candidate count (margin over K=20 for approx->fp64 rank safety)
#define SPH 2052 // fp16 pd row stride (halves)

// native clang vector type for nontemporal builtin (HIP float4 is a class)
typedef float nfloat4 __attribute__((ext_vector_type(4)));

// ---------------------------------------------------------------------------
// prep: xt[b][n][c] = x[b][c][n]  (fp32, 256B rows), plus norms in fp64+fp32.
// ---------------------------------------------------------------------------
__global__ __launch_bounds__(256) void prep_kernel(const float* __restrict__ x,
                                                   float* __restrict__ xt,
                                                   float* __restrict__ xxf,
                                                   double* __restrict__ xxd) {
    __shared__ float s_t[64][65];
    int b = blockIdx.x >> 5;
    int n0 = (blockIdx.x & 31) * 64;
    const float* xb = x + (size_t)b * CC * NN;
    int tid = threadIdx.x;
    int cq = tid >> 6;
    int nl = tid & 63;

#pragma unroll
    for (int r = 0; r < 16; ++r) {
        int c = r * 4 + cq;
        s_t[c][nl] = xb[c * NN + n0 + nl];
    }
    __syncthreads();

#pragma unroll
    for (int r = 0; r < 16; ++r) {
        int n = r * 4 + cq;
        xt[((size_t)b * NN + n0 + n) * CC + nl] = s_t[nl][n];
    }

    if (tid < 64) {
        double s = 0.0;
#pragma unroll
        for (int c = 0; c < CC; ++c) {
            double v = (double)s_t[c][tid];
            s += v * v;
        }
        xxd[b * NN + n0 + tid] = s;
        xxf[b * NN + n0 + tid] = (float)s;
    }
}

// ---------------------------------------------------------------------------
// knn v7: fp32-VALU fill (proven fastest; MFMA variants were gather-latency-
// bound, r4/r5) + fp16 pd in LDS. LDS 71.6KB -> 41KB => 3 blocks/CU
// (6 waves/SIMD, +50% latency hiding for the serial selection chains).
// Phase 1: block-cooperative fp32 distance fill, stored as fp16 (selection
//   quantization only -- fp16 ulp at |pd|~100 is 0.06 << rank-20..26 gaps;
//   exact fp64 refine does the final ranking).
// Phase 2: per-wave threshold selection, identical logic to the 602us
//   version, on dequantized values.
// Phase 3: fp64 refine; candidate rows read directly from global (L2-hot,
//   26 x 256B per wave), q-row broadcast from s_qT.
// ---------------------------------------------------------------------------
__global__ __launch_bounds__(512, 6) void knn_kernel(const float* __restrict__ x,
                                                     const float* __restrict__ xt,
                                                     const float* __restrict__ xxf,
                                                     const double* __restrict__ xxd,
                                                     int* __restrict__ idx_ws,
                                                     float* __restrict__ idx_out) {
    __shared__ __half s_pd[TQ][SPH];               // 32.8 KiB fp16 pd rows
    __shared__ __align__(16) float s_q[CC][TQ];    // 2 KiB, [c][q] for fill
    __shared__ __align__(16) float s_qT[TQ][CC];   // 2 KiB, [q][c] for phase 3
    __shared__ float s_sv[TQ][64];                 // survivor values
    __shared__ int   s_si[TQ][64];                 // survivor indices

    int tid = threadIdx.x;
    int b = blockIdx.x >> 8;                       // NN/TQ = 256 blocks/batch
    int n0 = (blockIdx.x & 255) * TQ;
    const float* xb = x + (size_t)b * CC * NN;

    {
        int c = tid >> 3, qq = tid & 7;
        float qv = xb[c * NN + n0 + qq];
        s_q[c][qq] = qv;
        s_qT[qq][c] = qv;
    }
    __syncthreads();

    // ---- phase 1: fill (thread owns 4 consecutive m for all 8 queries) ----
    {
        float4 xa = *(const float4*)(xxf + b * NN + n0);
        float4 xc = *(const float4*)(xxf + b * NN + n0 + 4);
        float xxn[TQ] = {xa.x, xa.y, xa.z, xa.w, xc.x, xc.y, xc.z, xc.w};

        int m = tid * 4;
        float acc[TQ][4];
#pragma unroll
        for (int q = 0; q < TQ; ++q)
#pragma unroll
            for (int i = 0; i < 4; ++i) acc[q][i] = 0.f;

        for (int c = 0; c < CC; ++c) {
            float4 xv = *(const float4*)(xb + c * NN + m);
            float4 qa = *(const float4*)(&s_q[c][0]);
            float4 qb = *(const float4*)(&s_q[c][4]);
            float xs[4] = {xv.x, xv.y, xv.z, xv.w};
            float qs[TQ] = {qa.x, qa.y, qa.z, qa.w, qb.x, qb.y, qb.z, qb.w};
#pragma unroll
            for (int q = 0; q < TQ; ++q)
#pragma unroll
                for (int i = 0; i < 4; ++i) acc[q][i] += qs[q] * xs[i];
        }
        float4 xm4 = *(const float4*)(xxf + b * NN + m);
        float xms[4] = {xm4.x, xm4.y, xm4.z, xm4.w};
#pragma unroll
        for (int q = 0; q < TQ; ++q) {
            float4 pdv;
            pdv.x = (2.f * acc[q][0] - xxn[q]) - xms[0];
            pdv.y = (2.f * acc[q][1] - xxn[q]) - xms[1];
            pdv.z = (2.f * acc[q][2] - xxn[q]) - xms[2];
            pdv.w = (2.f * acc[q][3] - xxn[q]) - xms[3];
            __half2 h01 = __floats2half2_rn(pdv.x, pdv.y);
            __half2 h23 = __floats2half2_rn(pdv.z, pdv.w);
            *(__half2*)(&s_pd[q][m]) = h01;
            *(__half2*)(&s_pd[q][m + 2]) = h23;
        }
    }
    __syncthreads();

    // ---- phase 2: per-wave selection ----
    int q = tid >> 6;
    int lane = tid & 63;
    const __half* pd = &s_pd[q][0];

    float v[32];
#pragma unroll
    for (int r = 0; r < 32; ++r) v[r] = __half2float(pd[lane + (r << 6)]);

    float lmax = v[0]; int lr = 0;
#pragma unroll
    for (int r = 1; r < 32; ++r)
        if (v[r] > lmax) { lmax = v[r]; lr = r; }              // strict > : lowest idx

    // tau = 26th-largest lane-max (values-only 64-lane bitonic, descending)
    float sv = lmax;
#pragma unroll
    for (int k = 2; k <= 64; k <<= 1) {
#pragma unroll
        for (int j = k >> 1; j > 0; j >>= 1) {
            float o = __shfl_xor(sv, j);
            bool dird = ((lane & k) == 0);
            bool first = ((lane & j) == 0);
            sv = (first == dird) ? fmaxf(sv, o) : fminf(sv, o);
        }
    }
    float tau = __shfl(sv, 25);

    int cnt = 0;
#pragma unroll
    for (int r = 0; r < 32; ++r) cnt += (v[r] >= tau) ? 1 : 0;
    int incl = cnt;
#pragma unroll
    for (int off = 1; off < 64; off <<= 1) {
        int o = __shfl_up(incl, off);
        if (lane >= off) incl += o;
    }
    int S = __shfl(incl, 63);

    float fv = -INFINITY;
    int fi = 0x7fffffff;
    if (S <= 64) {
        int w = incl - cnt;
#pragma unroll
        for (int r = 0; r < 32; ++r) {
            if (v[r] >= tau) { s_sv[q][w] = v[r]; s_si[q][w] = lane + (r << 6); ++w; }
        }
        if (lane < S) { fv = s_sv[q][lane]; fi = s_si[q][lane]; }
    } else {
        // pathological (mass ties): exact iterative top-26 extraction
        for (int t = 0; t < NC; ++t) {
            float bv = lmax; int bi = lane + (lr << 6);
#pragma unroll
            for (int off = 32; off; off >>= 1) {
                float ov = __shfl_xor(bv, off);
                int oi = __shfl_xor(bi, off);
                if (ov > bv || (ov == bv && oi < bi)) { bv = ov; bi = oi; }
            }
            if (lane == t) { fv = bv; fi = bi; }
            if ((bi & 63) == lane) {
                int rsel = bi >> 6;
#pragma unroll
                for (int r = 0; r < 32; ++r) if (r == rsel) v[r] = -INFINITY;
                lmax = v[0]; lr = 0;
#pragma unroll
                for (int r = 1; r < 32; ++r)
                    if (v[r] > lmax) { lmax = v[r]; lr = r; }
            }
        }
    }

    // 64-lane bitonic sort of (fv desc, fi asc) -> lanes 0..25 = approx top-26
#pragma unroll
    for (int k = 2; k <= 64; k <<= 1) {
#pragma unroll
        for (int j = k >> 1; j > 0; j >>= 1) {
            float ov = __shfl_xor(fv, j);
            int oi = __shfl_xor(fi, j);
            bool dird = ((lane & k) == 0);
            bool first = ((lane & j) == 0);
            bool better = (fv > ov) || (fv == ov && fi < oi);
            if (better != (first == dird)) { fv = ov; fi = oi; }
        }
    }

    // ---- phase 3: fp64 refine (direct global candidate rows, L2-hot) ----
    int nq = n0 + q;
    double accd = 0.0;
    if (lane < NC) {
        const float* crow = xt + (size_t)b * NN * CC + (size_t)fi * CC;
        const float* qrow = &s_qT[q][0];
        double a0 = 0.0, a1 = 0.0, a2 = 0.0, a3 = 0.0;
#pragma unroll
        for (int j = 0; j < 16; ++j) {
            float4 cv = *(const float4*)(crow + j * 4);
            float4 qv = *(const float4*)(qrow + j * 4);   // LDS b128 broadcast
            a0 = fma((double)qv.x, (double)cv.x, a0);
            a1 = fma((double)qv.y, (double)cv.y, a1);
            a2 = fma((double)qv.z, (double)cv.z, a2);
            a3 = fma((double)qv.w, (double)cv.w, a3);
        }
        accd = (a0 + a1) + (a2 + a3);
    }

    double val = -INFINITY;
    int idxq = 0x7fffffff;
    if (lane < NC) {
        val = 2.0 * accd - xxd[b * NN + nq] - xxd[b * NN + fi];
        idxq = fi;
    }

    // 32-lane fp64 bitonic (val desc, idx asc)
#pragma unroll
    for (int k = 2; k <= 32; k <<= 1) {
#pragma unroll
        for (int j = k >> 1; j > 0; j >>= 1) {
            double ov = __shfl_xor(val, j, 32);
            int oi = __shfl_xor(idxq, j, 32);
            bool dird = ((lane & k) == 0);
            bool first = ((lane & j) == 0);
            bool better = (val > ov) || (val == ov && idxq < oi);
            if (better != (first == dird)) { val = ov; idxq = oi; }
        }
    }

    if (lane < KK) {
        size_t obase = ((size_t)b * NN + nq) * KK;
        idx_ws[obase + lane] = idxq;
        idx_out[obase + lane] = (float)(idxq + b * NN);
    }
}

// ---------------------------------------------------------------------------
// x1: mean of top-14 of 20 gathered neighbor values, written channel-major
// as x1t[b][c][n]. (sum20 - six minima)/14, order-independent.
// ---------------------------------------------------------------------------
__global__ __launch_bounds__(256) void x1_kernel(const float* __restrict__ xt,
                                                 const int* __restrict__ idx_ws,
                                                 float* __restrict__ x1t) {
    __shared__ int s_idx[16][KK];
    __shared__ float s_out[64][17];
    int tid = threadIdx.x;
    int b = blockIdx.x >> 7;
    int n0 = (blockIdx.x & 127) * 16;
    const float* xtb = xt + (size_t)b * NN * CC;

    for (int i = tid; i < 16 * KK; i += 256)
        s_idx[i / KK][i % KK] = idx_ws[((size_t)b * NN + n0) * KK + i];
    __syncthreads();

    int pl = tid >> 6, c = tid & 63;
#pragma unroll
    for (int it = 0; it < 4; ++it) {
        int nl = it * 4 + pl;
        float vals[KK];
        float sum = 0.f;
#pragma unroll
        for (int j = 0; j < KK; ++j) {
            vals[j] = xtb[(size_t)s_idx[nl][j] * CC + c];
            sum += vals[j];
        }
#pragma unroll
        for (int t = 0; t < KK - K2; ++t) {
            float worst = INFINITY;
            int wj = 0;
#pragma unroll
            for (int j = 0; j < KK; ++j)
                if (vals[j] < worst) { worst = vals[j]; wj = j; }
            sum -= worst;
            vals[wj] = INFINITY;
        }
        s_out[c][nl] = sum / (float)K2;
    }
    __syncthreads();

    int cw = tid >> 2, nw = (tid & 3) * 4;
    float4 v = make_float4(s_out[cw][nw], s_out[cw][nw + 1],
                           s_out[cw][nw + 2], s_out[cw][nw + 3]);
    *(float4*)(&x1t[((size_t)b * CC + cw) * NN + n0 + nw]) = v;
}

// ---------------------------------------------------------------------------
// feat: float4-vectorized. feature[b,ch,n,j]:
//   ch <  64: x1t[b,ch,idx[b,n,j]] - x[b,ch,n]
//   ch >= 64: x[b,ch-64,n]
// Write-only 335 MB output -> non-temporal stores.
// ---------------------------------------------------------------------------
__global__ __launch_bounds__(256) void feat_kernel(const float* __restrict__ x,
                                                   const float* __restrict__ x1t,
                                                   const int* __restrict__ idx_ws,
                                                   float* __restrict__ out) {
    int bc = blockIdx.x;
    int b = bc >> 7, ch = bc & 127;
    const float* xb = x + (size_t)b * CC * NN;
    float* o = out + (size_t)bc * NN * KK;
    const int* idxb = idx_ws + (size_t)b * NN * KK;

    if (ch < CC) {
        const float* row = x1t + ((size_t)b * CC + ch) * NN;
        const float* xr = xb + ch * NN;
        for (int it = 0; it < 40; ++it) {
            unsigned e = (it * 256 + threadIdx.x) * 4;
            int4 id4 = *(const int4*)(idxb + e);
            nfloat4 o4;
            o4.x = row[id4.x] - xr[(e    ) / KK];
            o4.y = row[id4.y] - xr[(e + 1) / KK];
            o4.z = row[id4.z] - xr[(e + 2) / KK];
            o4.w = row[id4.w] - xr[(e + 3) / KK];
            __builtin_nontemporal_store(o4, (nfloat4*)(o + e));
        }
    } else {
        const float* xr = xb + (ch - CC) * NN;
        for (int it = 0; it < 40; ++it) {
            unsigned e = (it * 256 + threadIdx.x) * 4;
            nfloat4 o4;
            o4.x = xr[(e    ) / KK];
            o4.y = xr[(e + 1) / KK];
            o4.z = xr[(e + 2) / KK];
            o4.w = xr[(e + 3) / KK];
            __builtin_nontemporal_store(o4, (nfloat4*)(o + e));
        }
    }
}

// ---------------------------------------------------------------------------
extern "C" void kernel_launch(void* const* d_in, const int* in_sizes, int n_in,
                              void* d_out, int out_size, void* d_ws, size_t ws_size,
                              hipStream_t stream) {
    const float* x = (const float*)d_in[0];   // (B, C, N) fp32
    float* out = (float*)d_out;

    char* ws = (char*)d_ws;
    float* xt   = (float*)ws;                                   // B*N*C
    float* x1t  = (float*)(ws + (size_t)8388608);               // B*C*N
    double* xxd = (double*)(ws + (size_t)16777216);             // B*N
    float* xxf  = (float*)(ws + (size_t)17039360);              // B*N
    int* idx_ws = (int*)(ws + (size_t)17170432);                // B*N*K

    float* idx_out = out + (size_t)BB * 2 * CC * NN * KK;       // idx_flat tail

    prep_kernel<<<BB * (NN / 64), 256, 0, stream>>>(x, xt, xxf, xxd);
    knn_kernel<<<BB * (NN / TQ), 512, 0, stream>>>(x, xt, xxf, xxd, idx_ws, idx_out);
    x1_kernel<<<BB * (NN / 16), 256, 0, stream>>>(xt, idx_ws, x1t);
    feat_kernel<<<BB * 2 * CC, 256, 0, stream>>>(x, x1t, idx_ws, out);
}